// Round 10
// baseline (378.497 us; speedup 1.0000x reference)
//
#include <hip/hip_runtime.h>
#include <hip/hip_bf16.h>

#define PCHUNK 8192
#define NBK 1024      // hist width (padded); used buckets = ceil(100000/128) = 782
#define BSZ 128       // nodes per bucket
#define CAP 2560      // per-bucket edge capacity (mean 2046, +11 sigma)

__device__ inline float bf2f(unsigned int u16) { return __uint_as_float(u16 << 16); }
__device__ inline unsigned short f2bf(float f) {
    __hip_bfloat16 b = __float2bfloat16(f);
    return *(unsigned short*)&b;
}

typedef __attribute__((ext_vector_type(8))) short v8s;
typedef __attribute__((ext_vector_type(4))) float v4f;

// ---- fused graph build: edge partition (phase 1) + device barrier +
//      per-bucket CSR build + xw1 (phase 2). grid=256 co-resident blocks. ----
__global__ void __launch_bounds__(256, 1)
k_build(const int* __restrict__ src, const int* __restrict__ dst, int E, int nchunks,
        int* __restrict__ bucket_cnt, int* __restrict__ bar,
        unsigned int* __restrict__ buckets,
        int* __restrict__ offs, int* __restrict__ deg, float* __restrict__ dinv,
        int* __restrict__ csr,
        const float* __restrict__ x, const float* __restrict__ W1,
        unsigned short* __restrict__ A, int N, int NBb,
        float* __restrict__ zero_base, int zero_count) {
    __shared__ int hist[NBK];
    __shared__ int shift[NBK];
    __shared__ int cursor[NBK];
    __shared__ unsigned int staged_e[PCHUNK];
    __shared__ unsigned short staged_b[PCHUNK];
    __shared__ int wtot[4];
    __shared__ float W1s[6 * 64];
    __shared__ int dl[BSZ], cur[BSZ];
    __shared__ float dis[BSZ];
    __shared__ float xs[BSZ * 6];
    __shared__ int w0tot;

    int t = threadIdx.x;
    int lane = t & 63, wave = t >> 6;

    // zero pool region; stage W1 (used in phase 2)
    for (int i = blockIdx.x * 256 + t; i < zero_count; i += gridDim.x * 256)
        zero_base[i] = 0.f;
    for (int i = t; i < 6 * 64; i += 256) W1s[i] = W1[i];

    // ================= phase 1: partition one 8192-edge chunk =================
    if (blockIdx.x < (unsigned)nchunks) {
        int base = blockIdx.x * PCHUNK;
        int nE = E - base; if (nE > PCHUNK) nE = PCHUNK;
        for (int i = t; i < NBK; i += 256) hist[i] = 0;
        __syncthreads();
        int dreg[32];
        #pragma unroll
        for (int j = 0; j < 32; ++j) {
            int ii = t + j * 256;
            dreg[j] = (ii < nE) ? dst[base + ii] : -1;
        }
        #pragma unroll
        for (int j = 0; j < 32; ++j)
            if (dreg[j] >= 0) atomicAdd(&hist[dreg[j] >> 7], 1);
        __syncthreads();
        // wave-shfl scan: thread t owns hist[4t..4t+3]
        int h0 = hist[4 * t], h1 = hist[4 * t + 1], h2 = hist[4 * t + 2], h3 = hist[4 * t + 3];
        int p1 = h0 + h1, p2 = p1 + h2, s = p2 + h3;
        int si = s;
        #pragma unroll
        for (int off = 1; off < 64; off <<= 1) {
            int u = __shfl_up(si, off, 64);
            if (lane >= off) si += u;
        }
        if (lane == 63) wtot[wave] = si;
        __syncthreads();
        int woff = 0;
        #pragma unroll
        for (int w2 = 0; w2 < 4; ++w2) woff += (w2 < wave) ? wtot[w2] : 0;
        int ebase = woff + si - s;
        int ex[4] = {ebase, ebase + h0, ebase + p1, ebase + p2};
        int cn[4] = {h0, h1, h2, h3};
        #pragma unroll
        for (int j = 0; j < 4; ++j) {
            int bidx = 4 * t + j;
            cursor[bidx] = ex[j];
            if (cn[j] > 0) {
                int g = atomicAdd(&bucket_cnt[bidx], cn[j]);
                shift[bidx] = g - ex[j];
            }
        }
        __syncthreads();
        #pragma unroll
        for (int j = 0; j < 32; ++j) {
            if (dreg[j] >= 0) {
                int e = base + t + j * 256;
                int d = dreg[j];
                int b = d >> 7;
                int r = atomicAdd(&cursor[b], 1);
                staged_e[r] = (unsigned int)src[e] | ((unsigned int)(d & (BSZ - 1)) << 24);
                staged_b[r] = (unsigned short)b;
            }
        }
        __syncthreads();
        for (int i = t; i < nE; i += 256) {
            int b = staged_b[i];
            buckets[(size_t)b * CAP + shift[b] + i] = staged_e[i];
        }
    }

    // ================= device barrier (all 256 blocks co-resident) ============
    __threadfence();
    __syncthreads();
    if (t == 0) {
        atomicAdd(bar, 1);
        while (atomicAdd(bar, 0) < (int)gridDim.x) {}
    }
    __syncthreads();
    __threadfence();

    // ================= phase 2: per-bucket CSR + xw1 ==========================
    for (int b = blockIdx.x; b < NBb; b += gridDim.x) {
        __syncthreads();   // protect xs/dl/cur/dis from previous iteration readers
        int nb0 = b * BSZ;
        for (int i = t; i < BSZ * 6; i += 256) {
            int node = nb0 + i / 6;
            xs[i] = (node < N) ? x[(size_t)nb0 * 6 + i] : 0.f;
        }
        if (t < BSZ) dl[t] = 0;
        __syncthreads();
        int cnt = bucket_cnt[b];
        if (cnt > CAP) cnt = CAP;
        const unsigned int* bp = buckets + (size_t)b * CAP;
        for (int i = t; i < cnt; i += 256) atomicAdd(&dl[bp[i] >> 24], 1);
        __syncthreads();
        int v = (t < BSZ) ? dl[t] : 0;
        int si = v;
        #pragma unroll
        for (int off = 1; off < 64; off <<= 1) {
            int u = __shfl_up(si, off, 64);
            if (lane >= off) si += u;
        }
        if (t == 63) w0tot = si;
        __syncthreads();
        int ex = si - v + ((wave == 1) ? w0tot : 0);
        if (t < BSZ) {
            cur[t] = ex;
            float di = rsqrtf((float)v + 1.0f);
            dis[t] = di;
            int n = nb0 + t;
            if (n < N) { offs[n] = b * CAP + ex; deg[n] = v; dinv[n] = di; }
        }
        __syncthreads();
        int* cg = csr + (size_t)b * CAP;
        for (int i = t; i < cnt; i += 256) {
            unsigned int e = bp[i];
            int r = atomicAdd(&cur[e >> 24], 1);
            cg[r] = (int)(e & 0x00FFFFFFu);
        }
        int ch = t & 63, sub = t >> 6;
        for (int nl = sub; nl < BSZ; nl += 4) {
            int node = nb0 + nl;
            if (node < N) {
                float acc = 0.f;
                #pragma unroll
                for (int k = 0; k < 6; ++k) acc += xs[nl * 6 + k] * W1s[k * 64 + ch];
                A[(size_t)node * 64 + ch] = f2bf(acc * dis[nl]);
            }
        }
    }
}

// ---- pull conv1 fused with xw2 MFMA (verified R9 structure) ----
__global__ void k_pull1_xw2(const unsigned short* __restrict__ A, const int* __restrict__ csr,
                            const int* __restrict__ offs, const int* __restrict__ deg,
                            const float* __restrict__ dinv, const float* __restrict__ bias,
                            const float* __restrict__ W2, unsigned short* __restrict__ A2,
                            int N) {
    __shared__ unsigned short Ht[16][72];
    int t = threadIdx.x;
    int lane = t & 63, wave = t >> 6;
    int q = lane >> 4, m = lane & 15;
    int cbase = wave * 16;
    v8s b0h, b0l, b1h, b1l;
    #pragma unroll
    for (int j = 0; j < 8; ++j) {
        float w0 = W2[(q * 8 + j) * 64 + cbase + m];
        unsigned short h0 = f2bf(w0);
        b0h[j] = (short)h0;
        b0l[j] = (short)f2bf(w0 - bf2f(h0));
        float w1 = W2[(32 + q * 8 + j) * 64 + cbase + m];
        unsigned short h1 = f2bf(w1);
        b1h[j] = (short)h1;
        b1l[j] = (short)f2bf(w1 - bf2f(h1));
    }
    int n0 = blockIdx.x * 16;
    float bias_l = bias[lane];
    for (int r = 0; r < 4; ++r) {
        int nl = wave * 4 + r;
        int n = n0 + nl;
        if (n < N) {
            int base = offs[n], dg = deg[n];
            float acc = bf2f(A[((size_t)n << 6) + lane]);
            int i = 0;
            for (; i + 8 <= dg; i += 8) {
                int s0 = csr[base + i],     s1 = csr[base + i + 1];
                int s2 = csr[base + i + 2], s3 = csr[base + i + 3];
                int s4 = csr[base + i + 4], s5 = csr[base + i + 5];
                int s6 = csr[base + i + 6], s7 = csr[base + i + 7];
                float a0 = bf2f(A[((size_t)s0 << 6) + lane]);
                float a1 = bf2f(A[((size_t)s1 << 6) + lane]);
                float a2 = bf2f(A[((size_t)s2 << 6) + lane]);
                float a3 = bf2f(A[((size_t)s3 << 6) + lane]);
                float a4 = bf2f(A[((size_t)s4 << 6) + lane]);
                float a5 = bf2f(A[((size_t)s5 << 6) + lane]);
                float a6 = bf2f(A[((size_t)s6 << 6) + lane]);
                float a7 = bf2f(A[((size_t)s7 << 6) + lane]);
                acc += ((a0 + a1) + (a2 + a3)) + ((a4 + a5) + (a6 + a7));
            }
            for (; i < dg; ++i) acc += bf2f(A[((size_t)csr[base + i] << 6) + lane]);
            float v = fmaxf(dinv[n] * acc + bias_l, 0.f);
            Ht[nl][lane] = f2bf(v);
        }
    }
    __syncthreads();
    union { uint4 u; v8s s; } a0u, a1u;
    a0u.u = *(const uint4*)&Ht[m][q * 8];
    a1u.u = *(const uint4*)&Ht[m][32 + q * 8];
    v4f acc = {0.f, 0.f, 0.f, 0.f};
    acc = __builtin_amdgcn_mfma_f32_16x16x32_bf16(a0u.s, b0l, acc, 0, 0, 0);
    acc = __builtin_amdgcn_mfma_f32_16x16x32_bf16(a1u.s, b1l, acc, 0, 0, 0);
    acc = __builtin_amdgcn_mfma_f32_16x16x32_bf16(a0u.s, b0h, acc, 0, 0, 0);
    acc = __builtin_amdgcn_mfma_f32_16x16x32_bf16(a1u.s, b1h, acc, 0, 0, 0);
    #pragma unroll
    for (int r = 0; r < 4; ++r) {
        int node = n0 + q * 4 + r;
        if (node < N)
            A2[(size_t)node * 64 + cbase + m] = f2bf(acc[r] * dinv[node]);
    }
}

// pull conv2 fused with mean-pool accumulation; 16-deep gather batches
__global__ void k_pull_pool(const unsigned short* __restrict__ A, const int* __restrict__ csr,
                            const int* __restrict__ offs, const int* __restrict__ deg,
                            const float* __restrict__ dinv, const float* __restrict__ bias,
                            const int* __restrict__ batch, float* __restrict__ pool, int N) {
    int tid = threadIdx.x;
    int n = blockIdx.x * 4 + (tid >> 6);
    int lane = tid & 63;
    if (n >= N) return;
    int base = offs[n], dg = deg[n];
    float acc = bf2f(A[((size_t)n << 6) + lane]);
    int i = 0;
    for (; i + 16 <= dg; i += 16) {
        int s[16];
        #pragma unroll
        for (int j = 0; j < 16; ++j) s[j] = csr[base + i + j];
        float a[16];
        #pragma unroll
        for (int j = 0; j < 16; ++j) a[j] = bf2f(A[((size_t)s[j] << 6) + lane]);
        float t0 = ((a[0] + a[1]) + (a[2] + a[3])) + ((a[4] + a[5]) + (a[6] + a[7]));
        float t1 = ((a[8] + a[9]) + (a[10] + a[11])) + ((a[12] + a[13]) + (a[14] + a[15]));
        acc += t0 + t1;
    }
    for (; i + 8 <= dg; i += 8) {
        int s0 = csr[base + i],     s1 = csr[base + i + 1];
        int s2 = csr[base + i + 2], s3 = csr[base + i + 3];
        int s4 = csr[base + i + 4], s5 = csr[base + i + 5];
        int s6 = csr[base + i + 6], s7 = csr[base + i + 7];
        float a0 = bf2f(A[((size_t)s0 << 6) + lane]);
        float a1 = bf2f(A[((size_t)s1 << 6) + lane]);
        float a2 = bf2f(A[((size_t)s2 << 6) + lane]);
        float a3 = bf2f(A[((size_t)s3 << 6) + lane]);
        float a4 = bf2f(A[((size_t)s4 << 6) + lane]);
        float a5 = bf2f(A[((size_t)s5 << 6) + lane]);
        float a6 = bf2f(A[((size_t)s6 << 6) + lane]);
        float a7 = bf2f(A[((size_t)s7 << 6) + lane]);
        acc += ((a0 + a1) + (a2 + a3)) + ((a4 + a5) + (a6 + a7));
    }
    for (; i < dg; ++i) acc += bf2f(A[((size_t)csr[base + i] << 6) + lane]);
    float v = fmaxf(dinv[n] * acc + bias[lane], 0.f);
    atomicAdd(&pool[(size_t)batch[n] * 64 + lane], v);
}

// per-graph head, 4 graphs per block; lin1W staged in LDS
__global__ void k_final4(const float* __restrict__ pool, const int* __restrict__ batch,
                         int N, int G,
                         const int* __restrict__ lig, const int* __restrict__ add,
                         const int* __restrict__ base, const int* __restrict__ aryl,
                         const float* __restrict__ e_lig, const float* __restrict__ e_add,
                         const float* __restrict__ e_base, const float* __restrict__ e_aryl,
                         const float* __restrict__ lin1W, const float* __restrict__ lin1b,
                         const float* __restrict__ lin2W, const float* __restrict__ lin2b,
                         float* __restrict__ out) {
    __shared__ float Wl[128 * 64];   // 32 KB
    __shared__ float cat[4][128];
    int t = threadIdx.x;
    int c = t & 63, wv = t >> 6;
    for (int i = t; i < 128 * 64; i += 256) Wl[i] = lin1W[i];
    int g = blockIdx.x * 4 + wv;
    if (g < G) {
        int res = 0;
        if (c < 2) {
            int target = g + c;
            int lo = 0, hi = N;
            while (lo < hi) {
                int mid = (lo + hi) >> 1;
                if (batch[mid] < target) lo = mid + 1; else hi = mid;
            }
            res = lo;
        }
        int lo = __shfl(res, 0, 64), hi = __shfl(res, 1, 64);
        float invc = 1.0f / fmaxf((float)(hi - lo), 1.0f);
        cat[wv][c] = pool[(size_t)g * 64 + c] * invc;
        float ev;
        if (c < 16)      ev = e_lig[lig[g] * 16 + c];
        else if (c < 32) ev = e_add[add[g] * 16 + (c - 16)];
        else if (c < 48) ev = e_base[base[g] * 16 + (c - 32)];
        else             ev = e_aryl[aryl[g] * 16 + (c - 48)];
        cat[wv][64 + c] = ev;
    }
    __syncthreads();
    if (g < G) {
        float acc = lin1b[c];
        #pragma unroll
        for (int k = 0; k < 128; ++k) acc += cat[wv][k] * Wl[k * 64 + c];
        float p = fmaxf(acc, 0.f) * lin2W[c];
        #pragma unroll
        for (int off = 32; off > 0; off >>= 1) p += __shfl_down(p, off, 64);
        if (c == 0) out[g] = p + lin2b[0];
    }
}

extern "C" void kernel_launch(void* const* d_in, const int* in_sizes, int n_in,
                              void* d_out, int out_size, void* d_ws, size_t ws_size,
                              hipStream_t stream) {
    const float* x      = (const float*)d_in[0];
    const int*   ei     = (const int*)d_in[1];
    const int*   batch  = (const int*)d_in[2];
    const int*   lig    = (const int*)d_in[3];
    const int*   addi   = (const int*)d_in[4];
    const int*   basei  = (const int*)d_in[5];
    const int*   aryl   = (const int*)d_in[6];
    const float* e_lig  = (const float*)d_in[7];
    const float* e_add  = (const float*)d_in[8];
    const float* e_base = (const float*)d_in[9];
    const float* e_aryl = (const float*)d_in[10];
    const float* W1     = (const float*)d_in[11];
    const float* b1     = (const float*)d_in[12];
    const float* W2     = (const float*)d_in[13];
    const float* b2     = (const float*)d_in[14];
    const float* lin1W  = (const float*)d_in[15];
    const float* lin1b  = (const float*)d_in[16];
    const float* lin2W  = (const float*)d_in[17];
    const float* lin2b  = (const float*)d_in[18];
    float* out = (float*)d_out;

    const int N = in_sizes[0] / 6;
    const int E = in_sizes[1] / 2;
    const int G = in_sizes[3];
    const int* src = ei;
    const int* dst = ei + E;
    const int NBb = (N + BSZ - 1) / BSZ;   // 782 buckets

    // ---- workspace layout ----
    char* w = (char*)d_ws;
    size_t SA = (size_t)N * 64;
    unsigned short* A  = (unsigned short*)w;  w += SA * 2;  // Abar conv1 (bf16)
    unsigned short* A2 = (unsigned short*)w;  w += SA * 2;  // Abar conv2 (bf16)
    float* dinv = (float*)w;   w += (size_t)N * 4;
    int*   deg  = (int*)w;     w += (size_t)N * 4;
    int*   offs = (int*)w;     w += (size_t)N * 4;
    float* pool = (float*)w;   w += (size_t)G * 64 * 4;     // zeroed by k_build
    int* bucket_cnt = (int*)w; w += NBK * 4;                // zeroed by memset
    int* bar    = (int*)w;     w += 64;                     // zeroed by memset
    unsigned int* buckets = (unsigned int*)w;  w += (size_t)NBb * CAP * 4;
    int* csr    = (int*)w;     w += (size_t)NBb * CAP * 4;

    hipMemsetAsync(bucket_cnt, 0, NBK * 4 + 64, stream);

    const int nchunks = (E + PCHUNK - 1) / PCHUNK;   // 196 chunks
    k_build<<<256, 256, 0, stream>>>(src, dst, E, nchunks, bucket_cnt, bar, buckets,
                                     offs, deg, dinv, csr, x, W1, A, N, NBb,
                                     pool, G * 64);

    // conv1 pull + fused xw2 MFMA
    k_pull1_xw2<<<(N + 15) / 16, 256, 0, stream>>>(A, csr, offs, deg, dinv, b1, W2, A2, N);

    // conv2 + fused pooling
    k_pull_pool<<<(N + 3) / 4, 256, 0, stream>>>(A2, csr, offs, deg, dinv, b2, batch, pool, N);

    // head (4 graphs per block)
    k_final4<<<(G + 3) / 4, 256, 0, stream>>>(pool, batch, N, G, lig, addi, basei, aryl,
                                              e_lig, e_add, e_base, e_aryl,
                                              lin1W, lin1b, lin2W, lin2b, out);
}

// Round 11
// 291.011 us; speedup vs baseline: 1.3006x; 1.3006x over previous
//
#include <hip/hip_runtime.h>
#include <hip/hip_bf16.h>

#define PCHUNK 4096
#define NBK 1024      // hist width (padded); used buckets = ceil(100000/128) = 782
#define BSZ 128       // nodes per bucket
#define CAP 2560      // per-bucket edge capacity (mean 2046, +11 sigma)

__device__ inline float bf2f(unsigned int u16) { return __uint_as_float(u16 << 16); }
__device__ inline unsigned short f2bf(float f) {
    __hip_bfloat16 b = __float2bfloat16(f);
    return *(unsigned short*)&b;
}

typedef __attribute__((ext_vector_type(8))) short v8s;
typedef __attribute__((ext_vector_type(4))) float v4f;

// ---- phase 1: partition edges into 128-node dst-buckets; also zeroes pool (R9-proven) ----
__global__ void k_partition(const int* __restrict__ src, const int* __restrict__ dst, int E,
                            int* __restrict__ bucket_cnt, unsigned int* __restrict__ buckets,
                            float* __restrict__ zero_base, int zero_count) {
    __shared__ int hist[NBK];
    __shared__ int shift[NBK];
    __shared__ int cursor[NBK];
    __shared__ unsigned int staged_e[PCHUNK];
    __shared__ unsigned short staged_b[PCHUNK];
    __shared__ int wtot[4];
    int t = threadIdx.x;
    int lane = t & 63, wave = t >> 6;
    int base = blockIdx.x * PCHUNK;
    for (int i = blockIdx.x * 256 + t; i < zero_count; i += gridDim.x * 256)
        zero_base[i] = 0.f;
    for (int i = t; i < NBK; i += 256) hist[i] = 0;
    __syncthreads();
    int nE = E - base; if (nE > PCHUNK) nE = PCHUNK;
    for (int i = t; i < nE; i += 256) atomicAdd(&hist[dst[base + i] >> 7], 1);
    __syncthreads();
    int h0 = hist[4 * t], h1 = hist[4 * t + 1], h2 = hist[4 * t + 2], h3 = hist[4 * t + 3];
    int p1 = h0 + h1, p2 = p1 + h2, s = p2 + h3;
    int si = s;
    #pragma unroll
    for (int off = 1; off < 64; off <<= 1) {
        int u = __shfl_up(si, off, 64);
        if (lane >= off) si += u;
    }
    if (lane == 63) wtot[wave] = si;
    __syncthreads();
    int woff = 0;
    #pragma unroll
    for (int w2 = 0; w2 < 4; ++w2) woff += (w2 < wave) ? wtot[w2] : 0;
    int ebase = woff + si - s;
    int ex[4] = {ebase, ebase + h0, ebase + p1, ebase + p2};
    int cn[4] = {h0, h1, h2, h3};
    #pragma unroll
    for (int j = 0; j < 4; ++j) {
        int bidx = 4 * t + j;
        cursor[bidx] = ex[j];
        if (cn[j] > 0) {
            int g = atomicAdd(&bucket_cnt[bidx], cn[j]);
            shift[bidx] = g - ex[j];
        }
    }
    __syncthreads();
    for (int i = t; i < nE; i += 256) {
        int d = dst[base + i];
        int b = d >> 7;
        int r = atomicAdd(&cursor[b], 1);
        staged_e[r] = (unsigned int)src[base + i] | ((unsigned int)(d & (BSZ - 1)) << 24);
        staged_b[r] = (unsigned short)b;
    }
    __syncthreads();
    for (int i = t; i < nE; i += 256) {
        int b = staged_b[i];
        buckets[(size_t)b * CAP + shift[b] + i] = staged_e[i];
    }
}

// ---- phase 2: per-bucket CSR build + fused xw1 (R9-proven) ----
__global__ void k_bucket_csr_xw1(const unsigned int* __restrict__ buckets,
                                 const int* __restrict__ bucket_cnt,
                                 int* __restrict__ offs, int* __restrict__ deg,
                                 float* __restrict__ dinv, int* __restrict__ csr,
                                 const float* __restrict__ x, const float* __restrict__ W1,
                                 unsigned short* __restrict__ A, int N) {
    __shared__ int dl[BSZ], cur[BSZ];
    __shared__ float dis[BSZ];
    __shared__ float W1s[6 * 64];
    __shared__ float xs[BSZ * 6];
    __shared__ int w0tot;
    int b = blockIdx.x, t = threadIdx.x;
    int nb0 = b * BSZ;
    for (int i = t; i < 6 * 64; i += 256) W1s[i] = W1[i];
    for (int i = t; i < BSZ * 6; i += 256) {
        int node = nb0 + i / 6;
        xs[i] = (node < N) ? x[(size_t)nb0 * 6 + i] : 0.f;
    }
    if (t < BSZ) dl[t] = 0;
    __syncthreads();
    int cnt = bucket_cnt[b];
    if (cnt > CAP) cnt = CAP;
    const unsigned int* bp = buckets + (size_t)b * CAP;
    for (int i = t; i < cnt; i += 256) atomicAdd(&dl[bp[i] >> 24], 1);
    __syncthreads();
    int lane = t & 63, wave = t >> 6;
    int v = (t < BSZ) ? dl[t] : 0;
    int si = v;
    #pragma unroll
    for (int off = 1; off < 64; off <<= 1) {
        int u = __shfl_up(si, off, 64);
        if (lane >= off) si += u;
    }
    if (t == 63) w0tot = si;
    __syncthreads();
    int ex = si - v + ((wave == 1) ? w0tot : 0);
    if (t < BSZ) {
        cur[t] = ex;
        float di = rsqrtf((float)v + 1.0f);
        dis[t] = di;
        int n = nb0 + t;
        if (n < N) { offs[n] = b * CAP + ex; deg[n] = v; dinv[n] = di; }
    }
    __syncthreads();
    int* cg = csr + (size_t)b * CAP;
    for (int i = t; i < cnt; i += 256) {
        unsigned int e = bp[i];
        int r = atomicAdd(&cur[e >> 24], 1);
        cg[r] = (int)(e & 0x00FFFFFFu);
    }
    int ch = t & 63, sub = t >> 6;
    for (int nl = sub; nl < BSZ; nl += 4) {
        int node = nb0 + nl;
        if (node < N) {
            float acc = 0.f;
            #pragma unroll
            for (int k = 0; k < 6; ++k) acc += xs[nl * 6 + k] * W1s[k * 64 + ch];
            A[(size_t)node * 64 + ch] = f2bf(acc * dis[nl]);
        }
    }
}

// ---- pull conv1 + fused xw2 MFMA. EXPERIMENT: 2 channels/lane packed gather —
//      each wave pulls 2 nodes simultaneously (lane>>5 = node, lane&31 = ch-pair),
//      halving VMEM instructions per edge (1 gather + 1 csr load per 2 edges). ----
__global__ void k_pull1_xw2(const unsigned short* __restrict__ A, const int* __restrict__ csr,
                            const int* __restrict__ offs, const int* __restrict__ deg,
                            const float* __restrict__ dinv, const float* __restrict__ bias,
                            const float* __restrict__ W2, unsigned short* __restrict__ A2,
                            int N) {
    __shared__ unsigned short Ht[16][72];
    int t = threadIdx.x;
    int lane = t & 63, wave = t >> 6;
    int q = lane >> 4, m = lane & 15;
    int cbase = wave * 16;
    v8s b0h, b0l, b1h, b1l;
    #pragma unroll
    for (int j = 0; j < 8; ++j) {
        float w0 = W2[(q * 8 + j) * 64 + cbase + m];
        unsigned short h0 = f2bf(w0);
        b0h[j] = (short)h0;
        b0l[j] = (short)f2bf(w0 - bf2f(h0));
        float w1 = W2[(32 + q * 8 + j) * 64 + cbase + m];
        unsigned short h1 = f2bf(w1);
        b1h[j] = (short)h1;
        b1l[j] = (short)f2bf(w1 - bf2f(h1));
    }
    int n0 = blockIdx.x * 16;
    int half = lane >> 5;     // which node of the pair
    int cl = lane & 31;       // channel pair: channels 2cl, 2cl+1
    float2 bb = *(const float2*)(bias + 2 * cl);
    #pragma unroll
    for (int p = 0; p < 2; ++p) {
        int nl = wave * 4 + 2 * p + half;
        int n = n0 + nl;
        bool valid = n < N;
        int nc = valid ? n : N - 1;
        int base = offs[nc];
        int dg = valid ? deg[nc] : 0;
        int dgo = __shfl(dg, lane ^ 32, 64);
        int dgm = dg > dgo ? dg : dgo;
        unsigned int su = *(const unsigned int*)(A + ((size_t)nc << 6) + 2 * cl);
        float a0 = __uint_as_float(su << 16);
        float a1 = __uint_as_float(su & 0xffff0000u);
        int i = 0;
        for (; i + 8 <= dgm; i += 8) {
            unsigned int u[8];
            #pragma unroll
            for (int j = 0; j < 8; ++j) {
                unsigned int s = (unsigned int)csr[base + i + j];
                if (s >= (unsigned int)N) s = 0;   // tail reads past dg hit poison — clamp
                u[j] = *(const unsigned int*)(A + ((size_t)s << 6) + 2 * cl);
            }
            #pragma unroll
            for (int j = 0; j < 8; ++j) {
                unsigned int uu = (i + j < dg) ? u[j] : 0u;
                a0 += __uint_as_float(uu << 16);
                a1 += __uint_as_float(uu & 0xffff0000u);
            }
        }
        for (; i < dgm; ++i) {
            unsigned int s = (unsigned int)csr[base + i];
            if (s >= (unsigned int)N) s = 0;
            unsigned int uu = *(const unsigned int*)(A + ((size_t)s << 6) + 2 * cl);
            uu = (i < dg) ? uu : 0u;
            a0 += __uint_as_float(uu << 16);
            a1 += __uint_as_float(uu & 0xffff0000u);
        }
        float di = valid ? dinv[n] : 0.f;
        float v0 = fmaxf(fmaf(di, a0, bb.x), 0.f);
        float v1 = fmaxf(fmaf(di, a1, bb.y), 0.f);
        if (valid) {
            unsigned int pk = (unsigned int)f2bf(v0) | ((unsigned int)f2bf(v1) << 16);
            *(unsigned int*)&Ht[nl][2 * cl] = pk;
        }
    }
    __syncthreads();
    union { uint4 u; v8s s; } a0u, a1u;
    a0u.u = *(const uint4*)&Ht[m][q * 8];
    a1u.u = *(const uint4*)&Ht[m][32 + q * 8];
    v4f acc = {0.f, 0.f, 0.f, 0.f};
    acc = __builtin_amdgcn_mfma_f32_16x16x32_bf16(a0u.s, b0l, acc, 0, 0, 0);
    acc = __builtin_amdgcn_mfma_f32_16x16x32_bf16(a1u.s, b1l, acc, 0, 0, 0);
    acc = __builtin_amdgcn_mfma_f32_16x16x32_bf16(a0u.s, b0h, acc, 0, 0, 0);
    acc = __builtin_amdgcn_mfma_f32_16x16x32_bf16(a1u.s, b1h, acc, 0, 0, 0);
    #pragma unroll
    for (int r = 0; r < 4; ++r) {
        int node = n0 + q * 4 + r;
        if (node < N)
            A2[(size_t)node * 64 + cbase + m] = f2bf(acc[r] * dinv[node]);
    }
}

// pull conv2 + mean-pool (CONTROL: scalar form, R9-proven, 16-deep batches)
__global__ void k_pull_pool(const unsigned short* __restrict__ A, const int* __restrict__ csr,
                            const int* __restrict__ offs, const int* __restrict__ deg,
                            const float* __restrict__ dinv, const float* __restrict__ bias,
                            const int* __restrict__ batch, float* __restrict__ pool, int N) {
    int tid = threadIdx.x;
    int n = blockIdx.x * 4 + (tid >> 6);
    int lane = tid & 63;
    if (n >= N) return;
    int base = offs[n], dg = deg[n];
    float acc = bf2f(A[((size_t)n << 6) + lane]);
    int i = 0;
    for (; i + 16 <= dg; i += 16) {
        int s[16];
        #pragma unroll
        for (int j = 0; j < 16; ++j) s[j] = csr[base + i + j];
        float a[16];
        #pragma unroll
        for (int j = 0; j < 16; ++j) a[j] = bf2f(A[((size_t)s[j] << 6) + lane]);
        float t0 = ((a[0] + a[1]) + (a[2] + a[3])) + ((a[4] + a[5]) + (a[6] + a[7]));
        float t1 = ((a[8] + a[9]) + (a[10] + a[11])) + ((a[12] + a[13]) + (a[14] + a[15]));
        acc += t0 + t1;
    }
    for (; i + 8 <= dg; i += 8) {
        int s0 = csr[base + i],     s1 = csr[base + i + 1];
        int s2 = csr[base + i + 2], s3 = csr[base + i + 3];
        int s4 = csr[base + i + 4], s5 = csr[base + i + 5];
        int s6 = csr[base + i + 6], s7 = csr[base + i + 7];
        float a0 = bf2f(A[((size_t)s0 << 6) + lane]);
        float a1 = bf2f(A[((size_t)s1 << 6) + lane]);
        float a2 = bf2f(A[((size_t)s2 << 6) + lane]);
        float a3 = bf2f(A[((size_t)s3 << 6) + lane]);
        float a4 = bf2f(A[((size_t)s4 << 6) + lane]);
        float a5 = bf2f(A[((size_t)s5 << 6) + lane]);
        float a6 = bf2f(A[((size_t)s6 << 6) + lane]);
        float a7 = bf2f(A[((size_t)s7 << 6) + lane]);
        acc += ((a0 + a1) + (a2 + a3)) + ((a4 + a5) + (a6 + a7));
    }
    for (; i < dg; ++i) acc += bf2f(A[((size_t)csr[base + i] << 6) + lane]);
    float v = fmaxf(dinv[n] * acc + bias[lane], 0.f);
    atomicAdd(&pool[(size_t)batch[n] * 64 + lane], v);
}

// per-graph head, 4 graphs per block; lin1W staged in LDS
__global__ void k_final4(const float* __restrict__ pool, const int* __restrict__ batch,
                         int N, int G,
                         const int* __restrict__ lig, const int* __restrict__ add,
                         const int* __restrict__ base, const int* __restrict__ aryl,
                         const float* __restrict__ e_lig, const float* __restrict__ e_add,
                         const float* __restrict__ e_base, const float* __restrict__ e_aryl,
                         const float* __restrict__ lin1W, const float* __restrict__ lin1b,
                         const float* __restrict__ lin2W, const float* __restrict__ lin2b,
                         float* __restrict__ out) {
    __shared__ float Wl[128 * 64];
    __shared__ float cat[4][128];
    int t = threadIdx.x;
    int c = t & 63, wv = t >> 6;
    for (int i = t; i < 128 * 64; i += 256) Wl[i] = lin1W[i];
    int g = blockIdx.x * 4 + wv;
    if (g < G) {
        int res = 0;
        if (c < 2) {
            int target = g + c;
            int lo = 0, hi = N;
            while (lo < hi) {
                int mid = (lo + hi) >> 1;
                if (batch[mid] < target) lo = mid + 1; else hi = mid;
            }
            res = lo;
        }
        int lo = __shfl(res, 0, 64), hi = __shfl(res, 1, 64);
        float invc = 1.0f / fmaxf((float)(hi - lo), 1.0f);
        cat[wv][c] = pool[(size_t)g * 64 + c] * invc;
        float ev;
        if (c < 16)      ev = e_lig[lig[g] * 16 + c];
        else if (c < 32) ev = e_add[add[g] * 16 + (c - 16)];
        else if (c < 48) ev = e_base[base[g] * 16 + (c - 32)];
        else             ev = e_aryl[aryl[g] * 16 + (c - 48)];
        cat[wv][64 + c] = ev;
    }
    __syncthreads();
    if (g < G) {
        float acc = lin1b[c];
        #pragma unroll
        for (int k = 0; k < 128; ++k) acc += cat[wv][k] * Wl[k * 64 + c];
        float p = fmaxf(acc, 0.f) * lin2W[c];
        #pragma unroll
        for (int off = 32; off > 0; off >>= 1) p += __shfl_down(p, off, 64);
        if (c == 0) out[g] = p + lin2b[0];
    }
}

extern "C" void kernel_launch(void* const* d_in, const int* in_sizes, int n_in,
                              void* d_out, int out_size, void* d_ws, size_t ws_size,
                              hipStream_t stream) {
    const float* x      = (const float*)d_in[0];
    const int*   ei     = (const int*)d_in[1];
    const int*   batch  = (const int*)d_in[2];
    const int*   lig    = (const int*)d_in[3];
    const int*   addi   = (const int*)d_in[4];
    const int*   basei  = (const int*)d_in[5];
    const int*   aryl   = (const int*)d_in[6];
    const float* e_lig  = (const float*)d_in[7];
    const float* e_add  = (const float*)d_in[8];
    const float* e_base = (const float*)d_in[9];
    const float* e_aryl = (const float*)d_in[10];
    const float* W1     = (const float*)d_in[11];
    const float* b1     = (const float*)d_in[12];
    const float* W2     = (const float*)d_in[13];
    const float* b2     = (const float*)d_in[14];
    const float* lin1W  = (const float*)d_in[15];
    const float* lin1b  = (const float*)d_in[16];
    const float* lin2W  = (const float*)d_in[17];
    const float* lin2b  = (const float*)d_in[18];
    float* out = (float*)d_out;

    const int N = in_sizes[0] / 6;
    const int E = in_sizes[1] / 2;
    const int G = in_sizes[3];
    const int* src = ei;
    const int* dst = ei + E;
    const int NBb = (N + BSZ - 1) / BSZ;   // 782 buckets

    // ---- workspace layout ----
    char* w = (char*)d_ws;
    size_t SA = (size_t)N * 64;
    unsigned short* A  = (unsigned short*)w;  w += SA * 2;  // Abar conv1 (bf16)
    unsigned short* A2 = (unsigned short*)w;  w += SA * 2;  // Abar conv2 (bf16)
    float* dinv = (float*)w;   w += (size_t)N * 4;
    int*   deg  = (int*)w;     w += (size_t)N * 4;
    int*   offs = (int*)w;     w += (size_t)N * 4;
    float* pool = (float*)w;   w += (size_t)G * 64 * 4;     // zeroed by k_partition
    int* bucket_cnt = (int*)w; w += NBK * 4;                // zeroed by memset
    unsigned int* buckets = (unsigned int*)w;  w += (size_t)NBb * CAP * 4;
    int* csr    = (int*)w;     w += (size_t)NBb * CAP * 4;
    w += 4096;   // slack: packed pull reads up to dgm past a node's csr end

    hipMemsetAsync(bucket_cnt, 0, NBK * 4, stream);

    const int npart = (E + PCHUNK - 1) / PCHUNK;   // 391 blocks
    k_partition<<<npart, 256, 0, stream>>>(src, dst, E, bucket_cnt, buckets,
                                           pool, G * 64);
    k_bucket_csr_xw1<<<NBb, 256, 0, stream>>>(buckets, bucket_cnt,
                                              offs, deg, dinv, csr, x, W1, A, N);

    // conv1 pull (packed 2ch/lane experiment) + fused xw2 MFMA
    k_pull1_xw2<<<(N + 15) / 16, 256, 0, stream>>>(A, csr, offs, deg, dinv, b1, W2, A2, N);

    // conv2 + fused pooling (scalar control)
    k_pull_pool<<<(N + 3) / 4, 256, 0, stream>>>(A2, csr, offs, deg, dinv, b2, batch, pool, N);

    // head (4 graphs per block)
    k_final4<<<(G + 3) / 4, 256, 0, stream>>>(pool, batch, N, G, lig, addi, basei, aryl,
                                              e_lig, e_add, e_base, e_aryl,
                                              lin1W, lin1b, lin2W, lin2b, out);
}

// Round 12
// 258.686 us; speedup vs baseline: 1.4632x; 1.1250x over previous
//
#include <hip/hip_runtime.h>
#include <hip/hip_bf16.h>

#define PCHUNK 4096
#define NBK 1024      // hist width (padded); used buckets = ceil(100000/128) = 782
#define BSZ 128       // nodes per bucket
#define CAP 2560      // per-bucket edge capacity (mean 2046, +11 sigma)

__device__ inline float bf2f(unsigned int u16) { return __uint_as_float(u16 << 16); }
__device__ inline unsigned short f2bf(float f) {
    __hip_bfloat16 b = __float2bfloat16(f);
    return *(unsigned short*)&b;
}

typedef __attribute__((ext_vector_type(8))) short v8s;
typedef __attribute__((ext_vector_type(4))) float v4f;

// ---- phase 1: partition edges into 128-node dst-buckets; also zeroes pool (R9-proven) ----
__global__ void k_partition(const int* __restrict__ src, const int* __restrict__ dst, int E,
                            int* __restrict__ bucket_cnt, unsigned int* __restrict__ buckets,
                            float* __restrict__ zero_base, int zero_count) {
    __shared__ int hist[NBK];
    __shared__ int shift[NBK];
    __shared__ int cursor[NBK];
    __shared__ unsigned int staged_e[PCHUNK];
    __shared__ unsigned short staged_b[PCHUNK];
    __shared__ int wtot[4];
    int t = threadIdx.x;
    int lane = t & 63, wave = t >> 6;
    int base = blockIdx.x * PCHUNK;
    for (int i = blockIdx.x * 256 + t; i < zero_count; i += gridDim.x * 256)
        zero_base[i] = 0.f;
    for (int i = t; i < NBK; i += 256) hist[i] = 0;
    __syncthreads();
    int nE = E - base; if (nE > PCHUNK) nE = PCHUNK;
    for (int i = t; i < nE; i += 256) atomicAdd(&hist[dst[base + i] >> 7], 1);
    __syncthreads();
    int h0 = hist[4 * t], h1 = hist[4 * t + 1], h2 = hist[4 * t + 2], h3 = hist[4 * t + 3];
    int p1 = h0 + h1, p2 = p1 + h2, s = p2 + h3;
    int si = s;
    #pragma unroll
    for (int off = 1; off < 64; off <<= 1) {
        int u = __shfl_up(si, off, 64);
        if (lane >= off) si += u;
    }
    if (lane == 63) wtot[wave] = si;
    __syncthreads();
    int woff = 0;
    #pragma unroll
    for (int w2 = 0; w2 < 4; ++w2) woff += (w2 < wave) ? wtot[w2] : 0;
    int ebase = woff + si - s;
    int ex[4] = {ebase, ebase + h0, ebase + p1, ebase + p2};
    int cn[4] = {h0, h1, h2, h3};
    #pragma unroll
    for (int j = 0; j < 4; ++j) {
        int bidx = 4 * t + j;
        cursor[bidx] = ex[j];
        if (cn[j] > 0) {
            int g = atomicAdd(&bucket_cnt[bidx], cn[j]);
            shift[bidx] = g - ex[j];
        }
    }
    __syncthreads();
    for (int i = t; i < nE; i += 256) {
        int d = dst[base + i];
        int b = d >> 7;
        int r = atomicAdd(&cursor[b], 1);
        staged_e[r] = (unsigned int)src[base + i] | ((unsigned int)(d & (BSZ - 1)) << 24);
        staged_b[r] = (unsigned short)b;
    }
    __syncthreads();
    for (int i = t; i < nE; i += 256) {
        int b = staged_b[i];
        buckets[(size_t)b * CAP + shift[b] + i] = staged_e[i];
    }
}

// ---- phase 2: per-bucket CSR build + fused xw1 (R9-proven) ----
__global__ void k_bucket_csr_xw1(const unsigned int* __restrict__ buckets,
                                 const int* __restrict__ bucket_cnt,
                                 int* __restrict__ offs, int* __restrict__ deg,
                                 float* __restrict__ dinv, int* __restrict__ csr,
                                 const float* __restrict__ x, const float* __restrict__ W1,
                                 unsigned short* __restrict__ A, int N) {
    __shared__ int dl[BSZ], cur[BSZ];
    __shared__ float dis[BSZ];
    __shared__ float W1s[6 * 64];
    __shared__ float xs[BSZ * 6];
    __shared__ int w0tot;
    int b = blockIdx.x, t = threadIdx.x;
    int nb0 = b * BSZ;
    for (int i = t; i < 6 * 64; i += 256) W1s[i] = W1[i];
    for (int i = t; i < BSZ * 6; i += 256) {
        int node = nb0 + i / 6;
        xs[i] = (node < N) ? x[(size_t)nb0 * 6 + i] : 0.f;
    }
    if (t < BSZ) dl[t] = 0;
    __syncthreads();
    int cnt = bucket_cnt[b];
    if (cnt > CAP) cnt = CAP;
    const unsigned int* bp = buckets + (size_t)b * CAP;
    for (int i = t; i < cnt; i += 256) atomicAdd(&dl[bp[i] >> 24], 1);
    __syncthreads();
    int lane = t & 63, wave = t >> 6;
    int v = (t < BSZ) ? dl[t] : 0;
    int si = v;
    #pragma unroll
    for (int off = 1; off < 64; off <<= 1) {
        int u = __shfl_up(si, off, 64);
        if (lane >= off) si += u;
    }
    if (t == 63) w0tot = si;
    __syncthreads();
    int ex = si - v + ((wave == 1) ? w0tot : 0);
    if (t < BSZ) {
        cur[t] = ex;
        float di = rsqrtf((float)v + 1.0f);
        dis[t] = di;
        int n = nb0 + t;
        if (n < N) { offs[n] = b * CAP + ex; deg[n] = v; dinv[n] = di; }
    }
    __syncthreads();
    int* cg = csr + (size_t)b * CAP;
    for (int i = t; i < cnt; i += 256) {
        unsigned int e = bp[i];
        int r = atomicAdd(&cur[e >> 24], 1);
        cg[r] = (int)(e & 0x00FFFFFFu);
    }
    int ch = t & 63, sub = t >> 6;
    for (int nl = sub; nl < BSZ; nl += 4) {
        int node = nb0 + nl;
        if (node < N) {
            float acc = 0.f;
            #pragma unroll
            for (int k = 0; k < 6; ++k) acc += xs[nl * 6 + k] * W1s[k * 64 + ch];
            A[(size_t)node * 64 + ch] = f2bf(acc * dis[nl]);
        }
    }
}

// ---- pull conv1 + fused xw2 MFMA. 4 ch/lane packed gather: wave pulls 4 nodes
//      simultaneously (quarter=node, lane&15 = 4-ch group; 16 lanes = full row).
//      0.5 VMEM instr/edge, 8-deep batched. ----
__global__ void k_pull1_xw2(const unsigned short* __restrict__ A, const int* __restrict__ csr,
                            const int* __restrict__ offs, const int* __restrict__ deg,
                            const float* __restrict__ dinv, const float* __restrict__ bias,
                            const float* __restrict__ W2, unsigned short* __restrict__ A2,
                            int N) {
    __shared__ unsigned short Ht[16][72];
    int t = threadIdx.x;
    int lane = t & 63, wave = t >> 6;
    int q = lane >> 4, m = lane & 15;
    int cbase = wave * 16;
    v8s b0h, b0l, b1h, b1l;
    #pragma unroll
    for (int j = 0; j < 8; ++j) {
        float w0 = W2[(q * 8 + j) * 64 + cbase + m];
        unsigned short h0 = f2bf(w0);
        b0h[j] = (short)h0;
        b0l[j] = (short)f2bf(w0 - bf2f(h0));
        float w1 = W2[(32 + q * 8 + j) * 64 + cbase + m];
        unsigned short h1 = f2bf(w1);
        b1h[j] = (short)h1;
        b1l[j] = (short)f2bf(w1 - bf2f(h1));
    }
    int n0 = blockIdx.x * 16;
    // ---- pull: 4 nodes per wave (one per quarter q), channels 4m..4m+3 per lane ----
    int nl = wave * 4 + q;
    int n = n0 + nl;
    bool valid = n < N;
    int nc = valid ? n : N - 1;
    int base = offs[nc];
    int dg = valid ? deg[nc] : 0;
    int dgm = dg, o;
    o = __shfl_xor(dgm, 16, 64); dgm = dgm > o ? dgm : o;
    o = __shfl_xor(dgm, 32, 64); dgm = dgm > o ? dgm : o;
    uint2 su = *(const uint2*)(A + ((size_t)nc << 6) + 4 * m);
    float a0 = __uint_as_float(su.x << 16);
    float a1 = __uint_as_float(su.x & 0xffff0000u);
    float a2 = __uint_as_float(su.y << 16);
    float a3 = __uint_as_float(su.y & 0xffff0000u);
    int i = 0;
    for (; i + 8 <= dgm; i += 8) {
        uint2 u[8];
        #pragma unroll
        for (int j = 0; j < 8; ++j) {
            unsigned int s = (unsigned int)csr[base + i + j];
            if (s >= (unsigned int)N) s = 0;   // tail/poison clamp
            u[j] = *(const uint2*)(A + ((size_t)s << 6) + 4 * m);
        }
        #pragma unroll
        for (int j = 0; j < 8; ++j) {
            unsigned int ux = (i + j < dg) ? u[j].x : 0u;
            unsigned int uy = (i + j < dg) ? u[j].y : 0u;
            a0 += __uint_as_float(ux << 16);
            a1 += __uint_as_float(ux & 0xffff0000u);
            a2 += __uint_as_float(uy << 16);
            a3 += __uint_as_float(uy & 0xffff0000u);
        }
    }
    for (; i < dgm; ++i) {
        unsigned int s = (unsigned int)csr[base + i];
        if (s >= (unsigned int)N) s = 0;
        uint2 uu = *(const uint2*)(A + ((size_t)s << 6) + 4 * m);
        unsigned int ux = (i < dg) ? uu.x : 0u;
        unsigned int uy = (i < dg) ? uu.y : 0u;
        a0 += __uint_as_float(ux << 16);
        a1 += __uint_as_float(ux & 0xffff0000u);
        a2 += __uint_as_float(uy << 16);
        a3 += __uint_as_float(uy & 0xffff0000u);
    }
    float di = valid ? dinv[n] : 0.f;
    float4 bb = *(const float4*)(bias + 4 * m);
    float v0 = fmaxf(fmaf(di, a0, bb.x), 0.f);
    float v1 = fmaxf(fmaf(di, a1, bb.y), 0.f);
    float v2 = fmaxf(fmaf(di, a2, bb.z), 0.f);
    float v3 = fmaxf(fmaf(di, a3, bb.w), 0.f);
    if (valid) {
        uint2 pk;
        pk.x = (unsigned int)f2bf(v0) | ((unsigned int)f2bf(v1) << 16);
        pk.y = (unsigned int)f2bf(v2) | ((unsigned int)f2bf(v3) << 16);
        *(uint2*)&Ht[nl][4 * m] = pk;
    }
    __syncthreads();
    union { uint4 u; v8s s; } a0u, a1u;
    a0u.u = *(const uint4*)&Ht[m][q * 8];
    a1u.u = *(const uint4*)&Ht[m][32 + q * 8];
    v4f acc = {0.f, 0.f, 0.f, 0.f};
    acc = __builtin_amdgcn_mfma_f32_16x16x32_bf16(a0u.s, b0l, acc, 0, 0, 0);
    acc = __builtin_amdgcn_mfma_f32_16x16x32_bf16(a1u.s, b1l, acc, 0, 0, 0);
    acc = __builtin_amdgcn_mfma_f32_16x16x32_bf16(a0u.s, b0h, acc, 0, 0, 0);
    acc = __builtin_amdgcn_mfma_f32_16x16x32_bf16(a1u.s, b1h, acc, 0, 0, 0);
    #pragma unroll
    for (int r = 0; r < 4; ++r) {
        int node = n0 + q * 4 + r;
        if (node < N)
            A2[(size_t)node * 64 + cbase + m] = f2bf(acc[r] * dinv[node]);
    }
}

// ---- pull conv2 + mean-pool: same 4ch/lane packing; epilogue transposes
//      through LDS so pool atomics stay full-wave contiguous (R5 trap avoided) ----
__global__ void k_pull_pool(const unsigned short* __restrict__ A, const int* __restrict__ csr,
                            const int* __restrict__ offs, const int* __restrict__ deg,
                            const float* __restrict__ dinv, const float* __restrict__ bias,
                            const int* __restrict__ batch, float* __restrict__ pool, int N) {
    __shared__ float vt[4][4][64];
    int t = threadIdx.x;
    int lane = t & 63, wave = t >> 6;
    int q = lane >> 4, m = lane & 15;
    int n0 = blockIdx.x * 16;
    int nl = wave * 4 + q;
    int n = n0 + nl;
    bool valid = n < N;
    int nc = valid ? n : N - 1;
    int base = offs[nc];
    int dg = valid ? deg[nc] : 0;
    int dgm = dg, o;
    o = __shfl_xor(dgm, 16, 64); dgm = dgm > o ? dgm : o;
    o = __shfl_xor(dgm, 32, 64); dgm = dgm > o ? dgm : o;
    uint2 su = *(const uint2*)(A + ((size_t)nc << 6) + 4 * m);
    float a0 = __uint_as_float(su.x << 16);
    float a1 = __uint_as_float(su.x & 0xffff0000u);
    float a2 = __uint_as_float(su.y << 16);
    float a3 = __uint_as_float(su.y & 0xffff0000u);
    int i = 0;
    for (; i + 8 <= dgm; i += 8) {
        uint2 u[8];
        #pragma unroll
        for (int j = 0; j < 8; ++j) {
            unsigned int s = (unsigned int)csr[base + i + j];
            if (s >= (unsigned int)N) s = 0;
            u[j] = *(const uint2*)(A + ((size_t)s << 6) + 4 * m);
        }
        #pragma unroll
        for (int j = 0; j < 8; ++j) {
            unsigned int ux = (i + j < dg) ? u[j].x : 0u;
            unsigned int uy = (i + j < dg) ? u[j].y : 0u;
            a0 += __uint_as_float(ux << 16);
            a1 += __uint_as_float(ux & 0xffff0000u);
            a2 += __uint_as_float(uy << 16);
            a3 += __uint_as_float(uy & 0xffff0000u);
        }
    }
    for (; i < dgm; ++i) {
        unsigned int s = (unsigned int)csr[base + i];
        if (s >= (unsigned int)N) s = 0;
        uint2 uu = *(const uint2*)(A + ((size_t)s << 6) + 4 * m);
        unsigned int ux = (i < dg) ? uu.x : 0u;
        unsigned int uy = (i < dg) ? uu.y : 0u;
        a0 += __uint_as_float(ux << 16);
        a1 += __uint_as_float(ux & 0xffff0000u);
        a2 += __uint_as_float(uy << 16);
        a3 += __uint_as_float(uy & 0xffff0000u);
    }
    float di = valid ? dinv[n] : 0.f;
    float4 bb = *(const float4*)(bias + 4 * m);
    float4 vv;
    vv.x = fmaxf(fmaf(di, a0, bb.x), 0.f);
    vv.y = fmaxf(fmaf(di, a1, bb.y), 0.f);
    vv.z = fmaxf(fmaf(di, a2, bb.z), 0.f);
    vv.w = fmaxf(fmaf(di, a3, bb.w), 0.f);
    *(float4*)&vt[wave][q][4 * m] = vv;
    __syncthreads();
    int nw0 = n0 + wave * 4;
    #pragma unroll
    for (int r = 0; r < 4; ++r) {
        int nn = nw0 + r;
        if (nn < N) {
            float v = vt[wave][r][lane];
            atomicAdd(&pool[(size_t)batch[nn] * 64 + lane], v);
        }
    }
}

// per-graph head, 4 graphs per block; lin1W staged in LDS
__global__ void k_final4(const float* __restrict__ pool, const int* __restrict__ batch,
                         int N, int G,
                         const int* __restrict__ lig, const int* __restrict__ add,
                         const int* __restrict__ base, const int* __restrict__ aryl,
                         const float* __restrict__ e_lig, const float* __restrict__ e_add,
                         const float* __restrict__ e_base, const float* __restrict__ e_aryl,
                         const float* __restrict__ lin1W, const float* __restrict__ lin1b,
                         const float* __restrict__ lin2W, const float* __restrict__ lin2b,
                         float* __restrict__ out) {
    __shared__ float Wl[128 * 64];
    __shared__ float cat[4][128];
    int t = threadIdx.x;
    int c = t & 63, wv = t >> 6;
    for (int i = t; i < 128 * 64; i += 256) Wl[i] = lin1W[i];
    int g = blockIdx.x * 4 + wv;
    if (g < G) {
        int res = 0;
        if (c < 2) {
            int target = g + c;
            int lo = 0, hi = N;
            while (lo < hi) {
                int mid = (lo + hi) >> 1;
                if (batch[mid] < target) lo = mid + 1; else hi = mid;
            }
            res = lo;
        }
        int lo = __shfl(res, 0, 64), hi = __shfl(res, 1, 64);
        float invc = 1.0f / fmaxf((float)(hi - lo), 1.0f);
        cat[wv][c] = pool[(size_t)g * 64 + c] * invc;
        float ev;
        if (c < 16)      ev = e_lig[lig[g] * 16 + c];
        else if (c < 32) ev = e_add[add[g] * 16 + (c - 16)];
        else if (c < 48) ev = e_base[base[g] * 16 + (c - 32)];
        else             ev = e_aryl[aryl[g] * 16 + (c - 48)];
        cat[wv][64 + c] = ev;
    }
    __syncthreads();
    if (g < G) {
        float acc = lin1b[c];
        #pragma unroll
        for (int k = 0; k < 128; ++k) acc += cat[wv][k] * Wl[k * 64 + c];
        float p = fmaxf(acc, 0.f) * lin2W[c];
        #pragma unroll
        for (int off = 32; off > 0; off >>= 1) p += __shfl_down(p, off, 64);
        if (c == 0) out[g] = p + lin2b[0];
    }
}

extern "C" void kernel_launch(void* const* d_in, const int* in_sizes, int n_in,
                              void* d_out, int out_size, void* d_ws, size_t ws_size,
                              hipStream_t stream) {
    const float* x      = (const float*)d_in[0];
    const int*   ei     = (const int*)d_in[1];
    const int*   batch  = (const int*)d_in[2];
    const int*   lig    = (const int*)d_in[3];
    const int*   addi   = (const int*)d_in[4];
    const int*   basei  = (const int*)d_in[5];
    const int*   aryl   = (const int*)d_in[6];
    const float* e_lig  = (const float*)d_in[7];
    const float* e_add  = (const float*)d_in[8];
    const float* e_base = (const float*)d_in[9];
    const float* e_aryl = (const float*)d_in[10];
    const float* W1     = (const float*)d_in[11];
    const float* b1     = (const float*)d_in[12];
    const float* W2     = (const float*)d_in[13];
    const float* b2     = (const float*)d_in[14];
    const float* lin1W  = (const float*)d_in[15];
    const float* lin1b  = (const float*)d_in[16];
    const float* lin2W  = (const float*)d_in[17];
    const float* lin2b  = (const float*)d_in[18];
    float* out = (float*)d_out;

    const int N = in_sizes[0] / 6;
    const int E = in_sizes[1] / 2;
    const int G = in_sizes[3];
    const int* src = ei;
    const int* dst = ei + E;
    const int NBb = (N + BSZ - 1) / BSZ;   // 782 buckets

    // ---- workspace layout ----
    char* w = (char*)d_ws;
    size_t SA = (size_t)N * 64;
    unsigned short* A  = (unsigned short*)w;  w += SA * 2;  // Abar conv1 (bf16)
    unsigned short* A2 = (unsigned short*)w;  w += SA * 2;  // Abar conv2 (bf16)
    float* dinv = (float*)w;   w += (size_t)N * 4;
    int*   deg  = (int*)w;     w += (size_t)N * 4;
    int*   offs = (int*)w;     w += (size_t)N * 4;
    float* pool = (float*)w;   w += (size_t)G * 64 * 4;     // zeroed by k_partition
    int* bucket_cnt = (int*)w; w += NBK * 4;                // zeroed by memset
    unsigned int* buckets = (unsigned int*)w;  w += (size_t)NBb * CAP * 4;
    int* csr    = (int*)w;     w += (size_t)NBb * CAP * 4;
    w += 4096;   // slack: packed pull reads up to dgm past a node's csr end

    hipMemsetAsync(bucket_cnt, 0, NBK * 4, stream);

    const int npart = (E + PCHUNK - 1) / PCHUNK;   // 391 blocks
    k_partition<<<npart, 256, 0, stream>>>(src, dst, E, bucket_cnt, buckets,
                                           pool, G * 64);
    k_bucket_csr_xw1<<<NBb, 256, 0, stream>>>(buckets, bucket_cnt,
                                              offs, deg, dinv, csr, x, W1, A, N);

    // conv1 pull (packed 4ch/lane) + fused xw2 MFMA
    k_pull1_xw2<<<(N + 15) / 16, 256, 0, stream>>>(A, csr, offs, deg, dinv, b1, W2, A2, N);

    // conv2 + fused pooling (packed 4ch/lane, LDS-transposed contiguous atomics)
    k_pull_pool<<<(N + 15) / 16, 256, 0, stream>>>(A2, csr, offs, deg, dinv, b2, batch, pool, N);

    // head (4 graphs per block)
    k_final4<<<(G + 3) / 4, 256, 0, stream>>>(pool, batch, N, G, lig, addi, basei, aryl,
                                              e_lig, e_add, e_base, e_aryl,
                                              lin1W, lin1b, lin2W, lin2b, out);
}